// Round 5
// baseline (1079.476 us; speedup 1.0000x reference)
//
#include <hip/hip_runtime.h>

#define CCH 64      // channels
#define RPB 64      // rows per bucket (dst_local fits 6 bits)

// ---------------- zero int buffer ----------------
__global__ void k_zero(int* __restrict__ p, int n) {
    int i = blockIdx.x * blockDim.x + threadIdx.x;
    if (i < n) p[i] = 0;
}

// ---- bucket histogram (LDS-aggregated), buckets of RPB dst rows ----
__global__ void __launch_bounds__(256) k_bhist(const int* __restrict__ e0,
        const int* __restrict__ e1, const int* __restrict__ e2,
        int* __restrict__ cnt, int E, int NB) {
    int c = blockIdx.y;
    const int* dd = ((c == 0) ? e0 : (c == 1) ? e1 : e2) + E;
    int base = blockIdx.x * 4096;
    int nE = E - base; if (nE > 4096) nE = 4096;
    __shared__ int hist[1024];
    int t = threadIdx.x;
    for (int i = t; i < 1024; i += 256) hist[i] = 0;
    __syncthreads();
    for (int k = t; k < nE; k += 256) atomicAdd(&hist[dd[base + k] >> 6], 1);
    __syncthreads();
    for (int i = t; i < NB; i += 256)
        if (hist[i]) atomicAdd(&cnt[c * NB + i], hist[i]);
}

// ---- exclusive scan of NB (<=1024) bucket counts per conv ----
__global__ void __launch_bounds__(1024) k_bscan(const int* __restrict__ cnt,
        int* __restrict__ bstart, int* __restrict__ bpos, int NB, int E) {
    int c = blockIdx.x;
    int t = threadIdx.x;
    __shared__ int sm[1024];
    int v = (t < NB) ? cnt[c * NB + t] : 0;
    int orig = v;
    sm[t] = v;
    __syncthreads();
    #pragma unroll
    for (int off = 1; off < 1024; off <<= 1) {
        int u = (t >= off) ? sm[t - off] : 0;
        __syncthreads();
        sm[t] += u;
        __syncthreads();
    }
    int ex = sm[t] - orig;
    if (t < NB) { bstart[c * (NB + 1) + t] = ex; bpos[c * NB + t] = ex; }
    if (t == 0) bstart[c * (NB + 1) + NB] = E;
}

// ---- direct partition: one global atomic per edge, packed 4B record ----
__global__ void k_part(const int* __restrict__ e0, const int* __restrict__ e1,
                       const int* __restrict__ e2, int* __restrict__ bpos,
                       unsigned* __restrict__ bdata, int E, int NB) {
    int t = blockIdx.x * blockDim.x + threadIdx.x;
    if (t >= 3 * E) return;
    int c = (t >= 2 * E) ? 2 : (t >= E) ? 1 : 0;
    int e = t - c * E;
    const int* ed = (c == 0) ? e0 : (c == 1) ? e1 : e2;
    int s = ed[e];
    int d = ed[E + e];
    int b = d >> 6;
    int slot = atomicAdd(&bpos[c * NB + b], 1);
    bdata[(size_t)c * E + slot] = (unsigned)s | ((unsigned)(d & 63) << 16);
}

// ---- per-row degree from partitioned data -> dinv = rsqrt(deg+1) ----
__global__ void __launch_bounds__(256) k_rowdeg(const unsigned* __restrict__ bdata,
        const int* __restrict__ bstart, float* __restrict__ dinv,
        int E, int N, int NB) {
    int b = blockIdx.x, c = blockIdx.y;
    __shared__ int cnt[RPB];
    int t = threadIdx.x;
    if (t < RPB) cnt[t] = 0;
    __syncthreads();
    int beg = bstart[c * (NB + 1) + b], end = bstart[c * (NB + 1) + b + 1];
    const unsigned* bd = bdata + (size_t)c * E;
    for (int i = beg + t; i < end; i += 256) atomicAdd(&cnt[bd[i] >> 16], 1);
    __syncthreads();
    int row = b * RPB + t;
    if (t < RPB && row < N) dinv[c * N + row] = rsqrtf((float)(cnt[t] + 1));
}

// ---- h'[c,row,:] = (x_row . W_c) * dinv[c,row] ----
__global__ void __launch_bounds__(256) k_gemm_all(const float* __restrict__ xs_,
        const float* __restrict__ xg_, const float* __restrict__ W0,
        const float* __restrict__ W1, const float* __restrict__ W2,
        const float* __restrict__ dinv, float* __restrict__ h, int N) {
    int c = blockIdx.y;
    const float* x = (c == 2) ? xg_ : xs_;
    const float* W = (c == 0) ? W0 : (c == 1) ? W1 : W2;
    __shared__ float Ws[CCH * CCH];
    __shared__ float xsm[16 * CCH];
    int t = threadIdx.x;
    #pragma unroll
    for (int j = 0; j < 4; ++j) {
        int idx = j * 1024 + t * 4;
        *(float4*)(Ws + idx) = *(const float4*)(W + idx);
    }
    int row0 = blockIdx.x * 16;
    {
        int idx = t * 4;
        int r = row0 + (idx >> 6);
        float4 v = make_float4(0.f, 0.f, 0.f, 0.f);
        if (r < N) v = *(const float4*)(x + (size_t)r * CCH + (idx & 63));
        *(float4*)(xsm + idx) = v;
    }
    __syncthreads();
    int lane = t & 63;
    int wv = t >> 6;
    float a0 = 0.f, a1 = 0.f, a2 = 0.f, a3 = 0.f;
    #pragma unroll
    for (int k = 0; k < CCH; ++k) {
        float w = Ws[k * CCH + lane];
        a0 += xsm[(wv * 4 + 0) * CCH + k] * w;
        a1 += xsm[(wv * 4 + 1) * CCH + k] * w;
        a2 += xsm[(wv * 4 + 2) * CCH + k] * w;
        a3 += xsm[(wv * 4 + 3) * CCH + k] * w;
    }
    const float* dv = dinv + c * N;
    float* hc = h + (size_t)c * N * CCH;
    int r = row0 + wv * 4;
    if (r + 0 < N) hc[(size_t)(r + 0) * CCH + lane] = a0 * dv[r + 0];
    if (r + 1 < N) hc[(size_t)(r + 1) * CCH + lane] = a1 * dv[r + 1];
    if (r + 2 < N) hc[(size_t)(r + 2) * CCH + lane] = a2 * dv[r + 2];
    if (r + 3 < N) hc[(size_t)(r + 3) * CCH + lane] = a3 * dv[r + 3];
}

// ---- accumulate one conv's bucket edges into this wave's private LDS copy ----
// Wave wv owns contiguous quarter [lo,hi) of the bucket edge list. No atomics:
// within a wave, lane-unique LDS addresses; across waves, private copies.
__device__ __forceinline__ void agg_conv(const unsigned* __restrict__ bd,
        int beg, int end, const float* __restrict__ hc,
        const float* __restrict__ dv, float* __restrict__ accp,
        int wv, int lane) {
    int cnt = end - beg;
    int q = (cnt + 3) >> 2;
    int lo = beg + wv * q;
    int hi = lo + q; if (hi > end) hi = end; if (lo > end) lo = end;
    int i = lo;
    for (; i + 3 < hi; i += 4) {        // 4 gathers in flight per wave
        unsigned r0 = bd[i], r1 = bd[i + 1], r2 = bd[i + 2], r3 = bd[i + 3];
        float v0 = hc[(size_t)(r0 & 0xFFFFu) * CCH + lane] * dv[r0 >> 16];
        float v1 = hc[(size_t)(r1 & 0xFFFFu) * CCH + lane] * dv[r1 >> 16];
        float v2 = hc[(size_t)(r2 & 0xFFFFu) * CCH + lane] * dv[r2 >> 16];
        float v3 = hc[(size_t)(r3 & 0xFFFFu) * CCH + lane] * dv[r3 >> 16];
        accp[(r0 >> 16) * CCH + lane] += v0;
        accp[(r1 >> 16) * CCH + lane] += v1;
        accp[(r2 >> 16) * CCH + lane] += v2;
        accp[(r3 >> 16) * CCH + lane] += v3;
    }
    for (; i < hi; ++i) {
        unsigned r0 = bd[i];
        accp[(r0 >> 16) * CCH + lane] +=
            hc[(size_t)(r0 & 0xFFFFu) * CCH + lane] * dv[r0 >> 16];
    }
}

// ---- bucket aggregate + fused epilogue (self-loop + bias). 64 KB LDS,
//      4 private accumulator copies, deterministic 4-way reduce. ----
__global__ void __launch_bounds__(256) k_agg(const unsigned* __restrict__ bdata,
        const int* __restrict__ bstart, const float* __restrict__ h,
        const float* __restrict__ dinv,
        const float* __restrict__ b0, const float* __restrict__ b1,
        const float* __restrict__ b2,
        float* __restrict__ out, int N, int E, int NB) {
    int b = blockIdx.x;
    int grp = blockIdx.y;                     // 0 = star, 1 = gal
    __shared__ float acc[4 * RPB * CCH];      // 64 KB
    __shared__ float dva[RPB], dvb[RPB], bias[CCH];
    int t = threadIdx.x;
    int lane = t & 63, wv = t >> 6;
    size_t NC = (size_t)N * CCH;
    int row0 = b * RPB;
    float4 z4 = make_float4(0.f, 0.f, 0.f, 0.f);
    for (int i = t * 4; i < 4 * RPB * CCH; i += 1024) *(float4*)(acc + i) = z4;
    if (grp == 0) {
        if (t < RPB) {
            int r = row0 + t;
            dva[t] = (r < N) ? dinv[r] : 0.f;
            dvb[t] = (r < N) ? dinv[N + r] : 0.f;
        }
        if (t < CCH) bias[t] = b0[t] + b1[t];
    } else {
        if (t < RPB) {
            int r = row0 + t;
            dva[t] = (r < N) ? dinv[2 * N + r] : 0.f;
        }
        if (t < CCH) bias[t] = b2[t];
    }
    __syncthreads();
    float* accp = acc + wv * RPB * CCH;
    if (grp == 0) {
        agg_conv(bdata,     bstart[b],            bstart[b + 1],            h,      dva, accp, wv, lane);
        agg_conv(bdata + E, bstart[(NB + 1) + b], bstart[(NB + 1) + b + 1], h + NC, dvb, accp, wv, lane);
    } else {
        agg_conv(bdata + 2 * (size_t)E, bstart[2 * (NB + 1) + b],
                 bstart[2 * (NB + 1) + b + 1], h + 2 * NC, dva, accp, wv, lane);
    }
    __syncthreads();
    for (int r = wv; r < RPB; r += 4) {
        int row = row0 + r;
        if (row >= N) break;                  // wave-uniform
        int o4 = r * CCH + lane;
        float o = acc[o4] + acc[RPB * CCH + o4]
                + acc[2 * RPB * CCH + o4] + acc[3 * RPB * CCH + o4]
                + bias[lane];
        if (grp == 0) {
            o += h[(size_t)row * CCH + lane] * dva[r]
               + h[NC + (size_t)row * CCH + lane] * dvb[r];
            out[(size_t)row * CCH + lane] = o;
        } else {
            o += h[2 * NC + (size_t)row * CCH + lane] * dva[r];
            out[NC + (size_t)row * CCH + lane] = o;
        }
    }
}

extern "C" void kernel_launch(void* const* d_in, const int* in_sizes, int n_in,
                              void* d_out, int out_size, void* d_ws, size_t ws_size,
                              hipStream_t stream) {
    const float* x_star = (const float*)d_in[0];
    const float* x_gal  = (const float*)d_in[1];
    const int*   e_ssn  = (const int*)d_in[2];
    const int*   e_ssf  = (const int*)d_in[3];
    const int*   e_ggn  = (const int*)d_in[4];
    const float* W_ssn  = (const float*)d_in[5];
    const float* W_ssf  = (const float*)d_in[6];
    const float* W_ggn  = (const float*)d_in[7];
    const float* b_ssn  = (const float*)d_in[8];
    const float* b_ssf  = (const float*)d_in[9];
    const float* b_ggn  = (const float*)d_in[10];

    const int N  = in_sizes[0] / CCH;     // 50000 (src fits 16-bit pack)
    const int E  = in_sizes[2] / 2;       // 1000000
    const size_t NC = (size_t)N * CCH;
    const int NB = (N + RPB - 1) / RPB;   // 782 buckets per conv

    // workspace layout (16B-aligned partitions)
    float*    ws     = (float*)d_ws;
    float*    h      = ws;                               // 3*NC floats
    float*    dinv   = ws + 3 * NC;                      // 3*N floats
    unsigned* bdata  = (unsigned*)(dinv + 3 * N);        // 3*E uints
    int*      bcnt   = (int*)bdata + (size_t)3 * E;      // 3*NB
    int*      bstart = bcnt + 3 * NB;                    // 3*(NB+1)
    int*      bpos   = bstart + 3 * (NB + 1);            // 3*NB

    const int B = 256;

    k_zero<<<(3 * NB + B - 1) / B, B, 0, stream>>>(bcnt, 3 * NB);
    k_bhist<<<dim3((E + 4095) / 4096, 3), B, 0, stream>>>(e_ssn, e_ssf, e_ggn,
                                                          bcnt, E, NB);
    k_bscan<<<3, 1024, 0, stream>>>(bcnt, bstart, bpos, NB, E);
    k_part<<<(3 * E + B - 1) / B, B, 0, stream>>>(e_ssn, e_ssf, e_ggn,
                                                  bpos, bdata, E, NB);
    k_rowdeg<<<dim3(NB, 3), B, 0, stream>>>(bdata, bstart, dinv, E, N, NB);
    k_gemm_all<<<dim3((N + 15) / 16, 3), B, 0, stream>>>(x_star, x_gal,
                                                         W_ssn, W_ssf, W_ggn,
                                                         dinv, h, N);
    k_agg<<<dim3(NB, 2), B, 0, stream>>>(bdata, bstart, h, dinv,
                                         b_ssn, b_ssf, b_ggn,
                                         (float*)d_out, N, E, NB);
}

// Round 6
// 387.431 us; speedup vs baseline: 2.7862x; 2.7862x over previous
//
#include <hip/hip_runtime.h>
#include <hip/hip_fp16.h>

#define CCH 64      // channels
#define RPB 32      // rows per bucket (dst_local fits 5 bits)
#define PCH 8192    // edges per partition block
#define NBMAX 1568  // >= NB = ceil(50000/32) = 1563

// ---------------- zero int buffer ----------------
__global__ void k_zero(int* __restrict__ p, int n) {
    int i = blockIdx.x * blockDim.x + threadIdx.x;
    if (i < n) p[i] = 0;
}

// ---- pass A: per-block bucket histogram -> H[c][blk][b]; also cnt totals ----
__global__ void __launch_bounds__(256) k_hist(const int* __restrict__ e0,
        const int* __restrict__ e1, const int* __restrict__ e2,
        int* __restrict__ H, int* __restrict__ cnt, int E, int NB, int NBLK) {
    int c = blockIdx.y;
    const int* dd = ((c == 0) ? e0 : (c == 1) ? e1 : e2) + E;
    int base = blockIdx.x * PCH;
    int nE = E - base; if (nE > PCH) nE = PCH;
    __shared__ int hist[NBMAX];
    int t = threadIdx.x;
    for (int i = t; i < NB; i += 256) hist[i] = 0;
    __syncthreads();
    for (int k = t; k < nE; k += 256) atomicAdd(&hist[dd[base + k] >> 5], 1);
    __syncthreads();
    int* Hrow = H + ((size_t)c * NBLK + blockIdx.x) * NB;
    for (int i = t; i < NB; i += 256) {
        int h = hist[i];
        Hrow[i] = h;
        if (h) atomicAdd(&cnt[c * NB + i], h);
    }
}

// ---- exclusive scan of NB (<=2048) bucket totals per conv -> bstart ----
__global__ void __launch_bounds__(1024) k_bscan(const int* __restrict__ cnt,
        int* __restrict__ bstart, int NB, int E) {
    int c = blockIdx.x, t = threadIdx.x;
    __shared__ int sm[1024];
    int i0 = 2 * t, i1 = 2 * t + 1;
    int v0 = (i0 < NB) ? cnt[c * NB + i0] : 0;
    int v1 = (i1 < NB) ? cnt[c * NB + i1] : 0;
    sm[t] = v0 + v1;
    __syncthreads();
    #pragma unroll
    for (int off = 1; off < 1024; off <<= 1) {
        int u = (t >= off) ? sm[t - off] : 0;
        __syncthreads();
        sm[t] += u;
        __syncthreads();
    }
    int ex = sm[t] - (v0 + v1);
    if (i0 < NB) bstart[c * (NB + 1) + i0] = ex;
    if (i1 < NB) bstart[c * (NB + 1) + i1] = ex + v0;
    if (t == 0) bstart[c * (NB + 1) + NB] = E;
}

// ---- pass B: per-bucket scan over blocks: H <- bstart[b] + prefix(H) ----
// one wave per bucket; lane l covers blk=l and blk=64+l (NBLK <= 128).
__global__ void __launch_bounds__(256) k_colscan(int* __restrict__ H,
        const int* __restrict__ bstart, int NB, int NBLK) {
    int c = blockIdx.y;
    int b = blockIdx.x * 4 + (threadIdx.x >> 6);
    if (b >= NB) return;
    int l = threadIdx.x & 63;
    int* Hc = H + (size_t)c * NBLK * NB;
    int v0 = (l < NBLK) ? Hc[(size_t)l * NB + b] : 0;
    int v1 = (64 + l < NBLK) ? Hc[(size_t)(64 + l) * NB + b] : 0;
    int s0 = v0;
    #pragma unroll
    for (int off = 1; off < 64; off <<= 1) {
        int u = __shfl_up(s0, off, 64);
        if (l >= off) s0 += u;
    }
    int tot0 = __shfl(s0, 63, 64);
    int s1 = v1;
    #pragma unroll
    for (int off = 1; off < 64; off <<= 1) {
        int u = __shfl_up(s1, off, 64);
        if (l >= off) s1 += u;
    }
    int base = bstart[c * (NB + 1) + b];
    if (l < NBLK) Hc[(size_t)l * NB + b] = base + s0 - v0;
    if (64 + l < NBLK) Hc[(size_t)(64 + l) * NB + b] = base + tot0 + s1 - v1;
}

// ---- pass C: place edges into exclusive slot ranges (LDS cursors only) ----
__global__ void __launch_bounds__(256) k_part2(const int* __restrict__ e0,
        const int* __restrict__ e1, const int* __restrict__ e2,
        const int* __restrict__ H, unsigned* __restrict__ bdata,
        int E, int NB, int NBLK) {
    int c = blockIdx.y;
    const int* ed = (c == 0) ? e0 : (c == 1) ? e1 : e2;
    int base = blockIdx.x * PCH;
    int nE = E - base; if (nE > PCH) nE = PCH;
    __shared__ int cur[NBMAX];
    const int* Hrow = H + ((size_t)c * NBLK + blockIdx.x) * NB;
    int t = threadIdx.x;
    for (int i = t; i < NB; i += 256) cur[i] = Hrow[i];
    __syncthreads();
    unsigned* bo = bdata + (size_t)c * E;
    for (int k = t; k < nE; k += 256) {
        int s = ed[base + k];
        int d = ed[E + base + k];
        int slot = atomicAdd(&cur[d >> 5], 1);
        bo[slot] = (unsigned)s | ((unsigned)(d & 31) << 16);
    }
}

// ---- per-row degree from partitioned data -> dinv = rsqrt(deg+1) ----
__global__ void __launch_bounds__(256) k_rowdeg(const unsigned* __restrict__ bdata,
        const int* __restrict__ bstart, float* __restrict__ dinv,
        int E, int N, int NB) {
    int b = blockIdx.x, c = blockIdx.y;
    __shared__ int cnt[RPB];
    int t = threadIdx.x;
    if (t < RPB) cnt[t] = 0;
    __syncthreads();
    int beg = bstart[c * (NB + 1) + b], end = bstart[c * (NB + 1) + b + 1];
    const unsigned* bd = bdata + (size_t)c * E;
    for (int i = beg + t; i < end; i += 256) atomicAdd(&cnt[bd[i] >> 16], 1);
    __syncthreads();
    int row = b * RPB + t;
    if (t < RPB && row < N) dinv[c * N + row] = rsqrtf((float)(cnt[t] + 1));
}

// ---- h16[c,row,:] = fp16( (x_row . W_c) * dinv[c,row] ) ----
__global__ void __launch_bounds__(256) k_gemm_all(const float* __restrict__ xs_,
        const float* __restrict__ xg_, const float* __restrict__ W0,
        const float* __restrict__ W1, const float* __restrict__ W2,
        const float* __restrict__ dinv, __half* __restrict__ h16, int N) {
    int c = blockIdx.y;
    const float* x = (c == 2) ? xg_ : xs_;
    const float* W = (c == 0) ? W0 : (c == 1) ? W1 : W2;
    __shared__ float Ws[CCH * CCH];
    __shared__ float xsm[16 * CCH];
    int t = threadIdx.x;
    #pragma unroll
    for (int j = 0; j < 4; ++j) {
        int idx = j * 1024 + t * 4;
        *(float4*)(Ws + idx) = *(const float4*)(W + idx);
    }
    int row0 = blockIdx.x * 16;
    {
        int idx = t * 4;
        int r = row0 + (idx >> 6);
        float4 v = make_float4(0.f, 0.f, 0.f, 0.f);
        if (r < N) v = *(const float4*)(x + (size_t)r * CCH + (idx & 63));
        *(float4*)(xsm + idx) = v;
    }
    __syncthreads();
    int lane = t & 63;
    int wv = t >> 6;
    float a0 = 0.f, a1 = 0.f, a2 = 0.f, a3 = 0.f;
    #pragma unroll
    for (int k = 0; k < CCH; ++k) {
        float w = Ws[k * CCH + lane];
        a0 += xsm[(wv * 4 + 0) * CCH + k] * w;
        a1 += xsm[(wv * 4 + 1) * CCH + k] * w;
        a2 += xsm[(wv * 4 + 2) * CCH + k] * w;
        a3 += xsm[(wv * 4 + 3) * CCH + k] * w;
    }
    const float* dv = dinv + c * N;
    __half* hc = h16 + (size_t)c * N * CCH;
    int r = row0 + wv * 4;
    if (r + 0 < N) hc[(size_t)(r + 0) * CCH + lane] = __float2half(a0 * dv[r + 0]);
    if (r + 1 < N) hc[(size_t)(r + 1) * CCH + lane] = __float2half(a1 * dv[r + 1]);
    if (r + 2 < N) hc[(size_t)(r + 2) * CCH + lane] = __float2half(a2 * dv[r + 2]);
    if (r + 3 < N) hc[(size_t)(r + 3) * CCH + lane] = __float2half(a3 * dv[r + 3]);
}

// ---- accumulate one conv's bucket edges into this wave's private LDS copy ----
// Full wave per edge (lane = channel): lane-unique LDS addresses, no atomics.
__device__ __forceinline__ void agg16(const unsigned* __restrict__ bd,
        int beg, int end, const __half* __restrict__ hc,
        const float* __restrict__ dv, float* __restrict__ accp, int wv, int lane) {
    int cnt = end - beg;
    int q = (cnt + 3) >> 2;
    int lo = beg + wv * q;
    int hi = lo + q; if (hi > end) hi = end; if (lo > end) lo = end;
    int i = lo;
    for (; i + 7 < hi; i += 8) {          // 8 gathers in flight per wave
        unsigned r0 = bd[i],     r1 = bd[i + 1], r2 = bd[i + 2], r3 = bd[i + 3];
        unsigned r4 = bd[i + 4], r5 = bd[i + 5], r6 = bd[i + 6], r7 = bd[i + 7];
        float v0 = __half2float(hc[(size_t)(r0 & 0xFFFFu) * CCH + lane]) * dv[r0 >> 16];
        float v1 = __half2float(hc[(size_t)(r1 & 0xFFFFu) * CCH + lane]) * dv[r1 >> 16];
        float v2 = __half2float(hc[(size_t)(r2 & 0xFFFFu) * CCH + lane]) * dv[r2 >> 16];
        float v3 = __half2float(hc[(size_t)(r3 & 0xFFFFu) * CCH + lane]) * dv[r3 >> 16];
        float v4 = __half2float(hc[(size_t)(r4 & 0xFFFFu) * CCH + lane]) * dv[r4 >> 16];
        float v5 = __half2float(hc[(size_t)(r5 & 0xFFFFu) * CCH + lane]) * dv[r5 >> 16];
        float v6 = __half2float(hc[(size_t)(r6 & 0xFFFFu) * CCH + lane]) * dv[r6 >> 16];
        float v7 = __half2float(hc[(size_t)(r7 & 0xFFFFu) * CCH + lane]) * dv[r7 >> 16];
        accp[(r0 >> 16) * CCH + lane] += v0;
        accp[(r1 >> 16) * CCH + lane] += v1;
        accp[(r2 >> 16) * CCH + lane] += v2;
        accp[(r3 >> 16) * CCH + lane] += v3;
        accp[(r4 >> 16) * CCH + lane] += v4;
        accp[(r5 >> 16) * CCH + lane] += v5;
        accp[(r6 >> 16) * CCH + lane] += v6;
        accp[(r7 >> 16) * CCH + lane] += v7;
    }
    for (; i < hi; ++i) {
        unsigned r0 = bd[i];
        accp[(r0 >> 16) * CCH + lane] +=
            __half2float(hc[(size_t)(r0 & 0xFFFFu) * CCH + lane]) * dv[r0 >> 16];
    }
}

// ---- bucket aggregate + fused epilogue. 32 KB LDS, 4 private copies. ----
__global__ void __launch_bounds__(256) k_agg(const unsigned* __restrict__ bdata,
        const int* __restrict__ bstart, const __half* __restrict__ h16,
        const float* __restrict__ dinv,
        const float* __restrict__ b0, const float* __restrict__ b1,
        const float* __restrict__ b2,
        float* __restrict__ out, int N, int E, int NB) {
    int b = blockIdx.x;
    int grp = blockIdx.y;                     // 0 = star, 1 = gal
    __shared__ float acc[4 * RPB * CCH];      // 32 KB
    __shared__ float dva[RPB], dvb[RPB], bias[CCH];
    int t = threadIdx.x;
    int lane = t & 63, wv = t >> 6;
    size_t NC = (size_t)N * CCH;
    int row0 = b * RPB;
    float4 z4 = make_float4(0.f, 0.f, 0.f, 0.f);
    for (int i = t * 4; i < 4 * RPB * CCH; i += 1024) *(float4*)(acc + i) = z4;
    if (grp == 0) {
        if (t < RPB) {
            int r = row0 + t;
            dva[t] = (r < N) ? dinv[r] : 0.f;
            dvb[t] = (r < N) ? dinv[N + r] : 0.f;
        }
        if (t >= 64 && t < 64 + CCH) bias[t - 64] = b0[t - 64] + b1[t - 64];
    } else {
        if (t < RPB) {
            int r = row0 + t;
            dva[t] = (r < N) ? dinv[2 * N + r] : 0.f;
        }
        if (t >= 64 && t < 64 + CCH) bias[t - 64] = b2[t - 64];
    }
    __syncthreads();
    float* accp = acc + wv * RPB * CCH;
    if (grp == 0) {
        agg16(bdata,     bstart[b],            bstart[b + 1],            h16,      dva, accp, wv, lane);
        agg16(bdata + E, bstart[(NB + 1) + b], bstart[(NB + 1) + b + 1], h16 + NC, dvb, accp, wv, lane);
    } else {
        agg16(bdata + 2 * (size_t)E, bstart[2 * (NB + 1) + b],
              bstart[2 * (NB + 1) + b + 1], h16 + 2 * NC, dva, accp, wv, lane);
    }
    __syncthreads();
    for (int r = wv; r < RPB; r += 4) {       // wave-uniform row
        int row = row0 + r;
        if (row >= N) break;
        int o4 = r * CCH + lane;
        float o = acc[o4] + acc[RPB * CCH + o4]
                + acc[2 * RPB * CCH + o4] + acc[3 * RPB * CCH + o4]
                + bias[lane];
        if (grp == 0) {
            o += __half2float(h16[(size_t)row * CCH + lane]) * dva[r]
               + __half2float(h16[NC + (size_t)row * CCH + lane]) * dvb[r];
            out[(size_t)row * CCH + lane] = o;
        } else {
            o += __half2float(h16[2 * NC + (size_t)row * CCH + lane]) * dva[r];
            out[NC + (size_t)row * CCH + lane] = o;
        }
    }
}

static inline size_t align256(size_t x) { return (x + 255) & ~(size_t)255; }

extern "C" void kernel_launch(void* const* d_in, const int* in_sizes, int n_in,
                              void* d_out, int out_size, void* d_ws, size_t ws_size,
                              hipStream_t stream) {
    const float* x_star = (const float*)d_in[0];
    const float* x_gal  = (const float*)d_in[1];
    const int*   e_ssn  = (const int*)d_in[2];
    const int*   e_ssf  = (const int*)d_in[3];
    const int*   e_ggn  = (const int*)d_in[4];
    const float* W_ssn  = (const float*)d_in[5];
    const float* W_ssf  = (const float*)d_in[6];
    const float* W_ggn  = (const float*)d_in[7];
    const float* b_ssn  = (const float*)d_in[8];
    const float* b_ssf  = (const float*)d_in[9];
    const float* b_ggn  = (const float*)d_in[10];

    const int N  = in_sizes[0] / CCH;       // 50000 (src fits 16-bit pack)
    const int E  = in_sizes[2] / 2;         // 1000000
    const size_t NC = (size_t)N * CCH;
    const int NB   = (N + RPB - 1) / RPB;   // 1563 buckets per conv
    const int NBLK = (E + PCH - 1) / PCH;   // 123 partition blocks per conv

    // workspace layout
    char* w = (char*)d_ws;
    __half*   h16    = (__half*)w;   w += align256((size_t)3 * NC * 2);
    float*    dinv   = (float*)w;    w += align256((size_t)3 * N * 4);
    unsigned* bdata  = (unsigned*)w; w += align256((size_t)3 * E * 4);
    int*      H      = (int*)w;      w += align256((size_t)3 * NBLK * NB * 4);
    int*      cnt    = (int*)w;      w += align256((size_t)3 * NB * 4);
    int*      bstart = (int*)w;      w += align256((size_t)3 * (NB + 1) * 4);

    const int B = 256;

    k_zero<<<(3 * NB + B - 1) / B, B, 0, stream>>>(cnt, 3 * NB);
    k_hist<<<dim3(NBLK, 3), B, 0, stream>>>(e_ssn, e_ssf, e_ggn, H, cnt, E, NB, NBLK);
    k_bscan<<<3, 1024, 0, stream>>>(cnt, bstart, NB, E);
    k_colscan<<<dim3((NB + 3) / 4, 3), B, 0, stream>>>(H, bstart, NB, NBLK);
    k_part2<<<dim3(NBLK, 3), B, 0, stream>>>(e_ssn, e_ssf, e_ggn, H, bdata, E, NB, NBLK);
    k_rowdeg<<<dim3(NB, 3), B, 0, stream>>>(bdata, bstart, dinv, E, N, NB);
    k_gemm_all<<<dim3((N + 15) / 16, 3), B, 0, stream>>>(x_star, x_gal,
                                                         W_ssn, W_ssf, W_ggn,
                                                         dinv, h16, N);
    k_agg<<<dim3(NB, 2), B, 0, stream>>>(bdata, bstart, h16, dinv,
                                         b_ssn, b_ssf, b_ggn,
                                         (float*)d_out, N, E, NB);
}